// Round 1
// baseline (424.251 us; speedup 1.0000x reference)
//
#include <hip/hip_runtime.h>
#include <hip/hip_bf16.h>

// WaveNet-style dilated conv stack, MI355X gfx950.
// Per layer: causal dilated conv (K=3, 64->128ch) as MFMA GEMM (K=192),
// gated tanh*sigmoid, fused 1x1 (64x64) MFMA, residual. 10 launches.
// x ping-pongs: even layers write d_ws, odd layers write out slot 0.

#define CH 64
#define TLEN 16384
#define NB 8
#define BN 128
#define NLAYER 10

typedef __attribute__((ext_vector_type(4))) float f32x4;
typedef __attribute__((ext_vector_type(8))) short s16x8;

__device__ __forceinline__ unsigned short f2bf(float f) {
    union { float f; unsigned u; } v; v.f = f;
    unsigned r = v.u + 0x7fffu + ((v.u >> 16) & 1u);  // RNE
    return (unsigned short)(r >> 16);
}

__global__ __launch_bounds__(256, 2)
void wavenet_layer(const float* __restrict__ xin, float* __restrict__ xout,
                   float* __restrict__ skip,
                   const float* __restrict__ wconv, const float* __restrict__ bconv,
                   const float* __restrict__ wout, const float* __restrict__ bout,
                   int layer, int dil, int last)
{
    // X~ staging: 24 k-blocks (192 ck / 8) x BN timesteps x 8 bf16  = 48 KB
    __shared__ unsigned short xs[24 * BN * 8];
    // gated activation staging for the 1x1: 8 c-blocks x BN x 8 bf16 = 16 KB
    __shared__ unsigned short as_[8 * BN * 8];

    const int tid  = threadIdx.x;
    const int lane = tid & 63;
    const int wv   = tid >> 6;          // wave 0..3
    const int hrow = lane & 15;         // MFMA row/col within 16
    const int kgrp = lane >> 4;         // MFMA k-group 0..3
    const int b  = blockIdx.y;
    const int t0 = blockIdx.x * BN;

    const size_t xbase = (size_t)b * CH * TLEN;

    // ---- stage X~ into LDS: slice kk holds x[c][t0+n-kk*dil] at ck=kk*64+c ----
    for (int task = wv; task < 48; task += 4) {
        const int kk  = task >> 4;       // 0..2 dilation tap
        const int rem = task & 15;
        const int c8  = rem >> 1;        // channel block 0..7
        const int ng  = rem & 1;         // n-group 0..1
        const int n   = ng * 64 + lane;
        const int tg  = t0 + n - kk * dil;
        unsigned short v[8];
        #pragma unroll
        for (int j = 0; j < 8; ++j) v[j] = 0;
        if (tg >= 0) {
            const float* p = xin + xbase + (size_t)(c8 * 8) * TLEN + tg;
            #pragma unroll
            for (int j = 0; j < 8; ++j) v[j] = f2bf(p[(size_t)j * TLEN]);
        }
        s16x8 pk;
        #pragma unroll
        for (int j = 0; j < 8; ++j) pk[j] = (short)v[j];
        *reinterpret_cast<s16x8*>(&xs[(size_t)((kk * 8 + c8) * BN + n) * 8]) = pk;
    }

    // ---- preload conv A-fragments (weights) into registers ----
    // A lane layout: row o = mtile*16 + (lane&15), k = (lane>>4)*8 + j
    // W~[o][ck] with ck = kk*64 + c maps to wconv[o][c][2-kk] (causal pad).
    const float* Wc = wconv + (size_t)layer * 128 * CH * 3;
    const float* Bc = bconv + (size_t)layer * 128;
    s16x8 wa[2][6];
    #pragma unroll
    for (int m = 0; m < 2; ++m) {
        const int o = (m * 4 + wv) * 16 + hrow;   // wave w: rows w*16.. and 64+w*16..
        #pragma unroll
        for (int ks = 0; ks < 6; ++ks) {
            const int ck0 = ks * 32 + kgrp * 8;
            const int kkw = ck0 >> 6;             // dilation tap index
            const int c0  = ck0 & 63;
            const float* p = Wc + ((size_t)o * CH + c0) * 3 + (2 - kkw);
            s16x8 pk;
            #pragma unroll
            for (int j = 0; j < 8; ++j) pk[j] = (short)f2bf(p[j * 3]);
            wa[m][ks] = pk;
        }
    }
    float bt[4], bs[4];
    #pragma unroll
    for (int r = 0; r < 4; ++r) {
        const int row = kgrp * 4 + r;
        bt[r] = Bc[wv * 16 + row];
        bs[r] = Bc[64 + wv * 16 + row];
    }

    __syncthreads();

    // ---- conv GEMM: Y[128][BN] = W~[128][192] * X~[192][BN] ----
    f32x4 accT[8], accS[8];
    #pragma unroll
    for (int nt = 0; nt < 8; ++nt) {
        accT[nt] = (f32x4){0.f, 0.f, 0.f, 0.f};
        accS[nt] = (f32x4){0.f, 0.f, 0.f, 0.f};
    }
    #pragma unroll
    for (int nt = 0; nt < 8; ++nt) {
        #pragma unroll
        for (int ks = 0; ks < 6; ++ks) {
            const int kb = ks * 4 + kgrp;
            const s16x8 bf = *reinterpret_cast<const s16x8*>(
                &xs[(size_t)(kb * BN + nt * 16 + hrow) * 8]);
            accT[nt] = __builtin_amdgcn_mfma_f32_16x16x32_bf16(wa[0][ks], bf, accT[nt], 0, 0, 0);
            accS[nt] = __builtin_amdgcn_mfma_f32_16x16x32_bf16(wa[1][ks], bf, accS[nt], 0, 0, 0);
        }
    }

    // ---- gated activation, skip write, (last: residual write) ----
    // C/D layout: col n = lane&15, row = (lane>>4)*4 + r  [verified m89]
    #pragma unroll
    for (int nt = 0; nt < 8; ++nt) {
        #pragma unroll
        for (int r = 0; r < 4; ++r) {
            const float yt = accT[nt][r] + bt[r];
            const float ys = accS[nt][r] + bs[r];
            // tanh(yt) = 2*sigmoid(2*yt)-1 ; sigmoid via native exp + rcp
            const float th = 2.f * __builtin_amdgcn_rcpf(1.f + __expf(-2.f * yt)) - 1.f;
            const float sg = __builtin_amdgcn_rcpf(1.f + __expf(-ys));
            const float av = th * sg;
            const int c = wv * 16 + kgrp * 4 + r;
            const int n = nt * 16 + hrow;
            const size_t gi = xbase + (size_t)c * TLEN + t0 + n;
            skip[gi] = av;
            if (!last) {
                as_[(size_t)((c >> 3) * BN + n) * 8 + (c & 7)] = f2bf(av);
            } else {
                xout[gi] = av + xin[gi];   // last layer: no 1x1, residual direct
            }
        }
    }

    if (last) return;

    __syncthreads();

    // ---- 1x1 transform: out[64][BN] = Wout[64][64] * a[64][BN] + bias + residual ----
    const float* Wo = wout + (size_t)layer * CH * CH;
    const float* Bo = bout + (size_t)layer * CH;
    s16x8 wa2[2];
    #pragma unroll
    for (int ks = 0; ks < 2; ++ks) {
        const int o = wv * 16 + hrow;
        const float* p = Wo + (size_t)o * CH + ks * 32 + kgrp * 8;
        s16x8 pk;
        #pragma unroll
        for (int j = 0; j < 8; ++j) pk[j] = (short)f2bf(p[j]);
        wa2[ks] = pk;
    }
    float bo[4];
    #pragma unroll
    for (int r = 0; r < 4; ++r) bo[r] = Bo[wv * 16 + kgrp * 4 + r];

    #pragma unroll
    for (int nt = 0; nt < 8; ++nt) {
        f32x4 acc = (f32x4){0.f, 0.f, 0.f, 0.f};
        #pragma unroll
        for (int ks = 0; ks < 2; ++ks) {
            const s16x8 bf = *reinterpret_cast<const s16x8*>(
                &as_[(size_t)((ks * 4 + kgrp) * BN + nt * 16 + hrow) * 8]);
            acc = __builtin_amdgcn_mfma_f32_16x16x32_bf16(wa2[ks], bf, acc, 0, 0, 0);
        }
        #pragma unroll
        for (int r = 0; r < 4; ++r) {
            const int o = wv * 16 + kgrp * 4 + r;
            const int n = nt * 16 + hrow;
            const size_t gi = xbase + (size_t)o * TLEN + t0 + n;
            xout[gi] = acc[r] + bo[r] + xin[gi];
        }
    }
}

extern "C" void kernel_launch(void* const* d_in, const int* in_sizes, int n_in,
                              void* d_out, int out_size, void* d_ws, size_t ws_size,
                              hipStream_t stream)
{
    const float* x  = (const float*)d_in[0];
    const float* wc = (const float*)d_in[1];
    const float* bc = (const float*)d_in[2];
    const float* wo = (const float*)d_in[3];
    const float* bo = (const float*)d_in[4];
    float* out = (float*)d_out;
    float* ws  = (float*)d_ws;       // needs >= 8*64*16384*4 = 33.6 MB
    const size_t plane = (size_t)NB * CH * TLEN;

    dim3 grid(TLEN / BN, NB), block(256);
    for (int i = 0; i < NLAYER; ++i) {
        // x ping-pong: even layers -> ws, odd layers -> out slot 0 (layer 9 lands in slot 0)
        const float* xi = (i == 0) ? x : ((i & 1) ? ws : out);
        float* xo = (i & 1) ? out : ws;
        float* skip = out + (size_t)(1 + i) * plane;
        wavenet_layer<<<grid, block, 0, stream>>>(xi, xo, skip, wc, bc, wo, bo,
                                                  i, 1 << i, (i == NLAYER - 1) ? 1 : 0);
    }
}

// Round 2
// 333.433 us; speedup vs baseline: 1.2724x; 1.2724x over previous
//
#include <hip/hip_runtime.h>
#include <hip/hip_bf16.h>

// WaveNet dilated conv stack, MI355X gfx950. Round 2:
//  - LDS 64KB->48KB (alias 1x1 staging onto conv staging) -> 3 blocks/CU
//  - single-copy staging for dil<=64 (1x global read instead of 3x)
//  - weights pre-packed to bf16 A-fragment order in d_ws by a prep kernel

#define CH 64
#define TLEN 16384
#define NB 8
#define BN 128
#define NLAYER 10

typedef __attribute__((ext_vector_type(4))) float f32x4;
typedef __attribute__((ext_vector_type(8))) short s16x8;

__device__ __forceinline__ unsigned short f2bf(float f) {
    union { float f; unsigned u; } v; v.f = f;
    unsigned r = v.u + 0x7fffu + ((v.u >> 16) & 1u);  // RNE
    return (unsigned short)(r >> 16);
}

#define NCONV (NLAYER * 4 * 2 * 6 * 64 * 8)   // 245760 bf16 = 10 layers of 128x192
#define NOUT  (NLAYER * 4 * 2 * 64 * 8)       // 40960  bf16 = 10 layers of 64x64

// Pack conv + 1x1 weights into bf16, laid out exactly as per-(wave,lane) MFMA
// A-fragments so the layer kernel loads them as 16B vectors.
__global__ void pack_weights(const float* __restrict__ wconv,
                             const float* __restrict__ wout,
                             unsigned short* __restrict__ wcpk,
                             unsigned short* __restrict__ wopk)
{
    int idx = blockIdx.x * 256 + threadIdx.x;
    if (idx < NCONV) {
        int j = idx & 7, t = idx >> 3;
        int lane = t & 63; t >>= 6;
        int ks = t % 6;   t /= 6;
        int m  = t & 1;   t >>= 1;
        int wv = t & 3;   int l = t >> 2;
        int o  = (m * 4 + wv) * 16 + (lane & 15);
        int ck = ks * 32 + (lane >> 4) * 8 + j;
        int kk = ck >> 6, c = ck & 63;
        wcpk[idx] = f2bf(wconv[(((size_t)l * 128 + o) * CH + c) * 3 + (2 - kk)]);
    } else if (idx < NCONV + NOUT) {
        int id = idx - NCONV;
        int j = id & 7, t = id >> 3;
        int lane = t & 63; t >>= 6;
        int ks = t & 1;    t >>= 1;
        int wv = t & 3;    int l = t >> 2;
        int o  = wv * 16 + (lane & 15);
        int c  = ks * 32 + (lane >> 4) * 8 + j;
        wopk[id] = f2bf(wout[((size_t)l * CH + o) * CH + c]);
    }
}

template<bool SINGLE>
__global__ __launch_bounds__(256, 3)
void wavenet_layer(const float* __restrict__ xin, float* __restrict__ xout,
                   float* __restrict__ skip,
                   const unsigned short* __restrict__ wcpk,
                   const unsigned short* __restrict__ wopk,
                   const float* __restrict__ bconv, const float* __restrict__ bout,
                   int layer, int dil, int last)
{
    // 48KB. SINGLE mode uses [8 c-blocks][NW<=256][8ch]; 3-tap uses [24 kb][BN][8].
    // The 1x1 activation staging (16KB) aliases the front (xs dead by then).
    __shared__ unsigned short xs[24 * BN * 8];
    unsigned short* as_ = xs;

    const int tid  = threadIdx.x;
    const int lane = tid & 63;
    const int wv   = tid >> 6;
    const int hrow = lane & 15;
    const int kgrp = lane >> 4;
    const int b  = blockIdx.y;
    const int t0 = blockIdx.x * BN;
    const size_t xbase = (size_t)b * CH * TLEN;
    const int NW = BN + 2 * dil;   // single-copy width (<=256 when dil<=64)

    // ---- stage X into LDS ----
    if (SINGLE) {
        #pragma unroll
        for (int c8 = 0; c8 < 8; ++c8) {
            for (int np = tid; np < NW; np += 256) {
                const int tg = t0 - 2 * dil + np;
                s16x8 pk = {0, 0, 0, 0, 0, 0, 0, 0};
                if (tg >= 0) {
                    const float* p = xin + xbase + (size_t)(c8 * 8) * TLEN + tg;
                    #pragma unroll
                    for (int j = 0; j < 8; ++j) pk[j] = (short)f2bf(p[(size_t)j * TLEN]);
                }
                *reinterpret_cast<s16x8*>(&xs[(size_t)(c8 * NW + np) * 8]) = pk;
            }
        }
    } else {
        for (int task = wv; task < 48; task += 4) {
            const int kk  = task >> 4;
            const int rem = task & 15;
            const int c8  = rem >> 1;
            const int ng  = rem & 1;
            const int n   = ng * 64 + lane;
            const int tg  = t0 + n - kk * dil;
            s16x8 pk = {0, 0, 0, 0, 0, 0, 0, 0};
            if (tg >= 0) {
                const float* p = xin + xbase + (size_t)(c8 * 8) * TLEN + tg;
                #pragma unroll
                for (int j = 0; j < 8; ++j) pk[j] = (short)f2bf(p[(size_t)j * TLEN]);
            }
            *reinterpret_cast<s16x8*>(&xs[(size_t)((kk * 8 + c8) * BN + n) * 8]) = pk;
        }
    }

    // ---- conv A-fragments from packed weights (16B vector loads) ----
    s16x8 wa[2][6];
    {
        const unsigned short* base =
            wcpk + ((size_t)(layer * 4 + wv) * 768 + lane) * 8;
        #pragma unroll
        for (int m = 0; m < 2; ++m)
            #pragma unroll
            for (int ks = 0; ks < 6; ++ks)
                wa[m][ks] = *reinterpret_cast<const s16x8*>(base + (size_t)(m * 6 + ks) * 512);
    }
    const float* Bc = bconv + (size_t)layer * 128;
    float bt[4], bs[4];
    #pragma unroll
    for (int r = 0; r < 4; ++r) {
        bt[r] = Bc[wv * 16 + kgrp * 4 + r];
        bs[r] = Bc[64 + wv * 16 + kgrp * 4 + r];
    }

    __syncthreads();

    // ---- conv GEMM: Y[128][BN] = W~[128][192] * X~[192][BN] ----
    f32x4 accT[8], accS[8];
    #pragma unroll
    for (int nt = 0; nt < 8; ++nt) {
        accT[nt] = (f32x4){0.f, 0.f, 0.f, 0.f};
        accS[nt] = (f32x4){0.f, 0.f, 0.f, 0.f};
    }
    #pragma unroll
    for (int nt = 0; nt < 8; ++nt) {
        #pragma unroll
        for (int ks = 0; ks < 6; ++ks) {
            const int kb = ks * 4 + kgrp;
            const unsigned short* bp;
            if (SINGLE) {
                const int kk = kb >> 3, c8i = kb & 7;    // ck=kb*8: tap, channel block
                bp = &xs[(size_t)(c8i * NW + nt * 16 + hrow + (2 - kk) * dil) * 8];
            } else {
                bp = &xs[(size_t)(kb * BN + nt * 16 + hrow) * 8];
            }
            const s16x8 bf = *reinterpret_cast<const s16x8*>(bp);
            accT[nt] = __builtin_amdgcn_mfma_f32_16x16x32_bf16(wa[0][ks], bf, accT[nt], 0, 0, 0);
            accS[nt] = __builtin_amdgcn_mfma_f32_16x16x32_bf16(wa[1][ks], bf, accS[nt], 0, 0, 0);
        }
    }

    __syncthreads();   // xs reads complete (as_ aliases xs)

    // ---- gated activation, skip write ----
    // C/D: col n = lane&15, row = (lane>>4)*4 + r
    #pragma unroll
    for (int nt = 0; nt < 8; ++nt) {
        #pragma unroll
        for (int r = 0; r < 4; ++r) {
            const float yt = accT[nt][r] + bt[r];
            const float ys = accS[nt][r] + bs[r];
            const float th = 2.f * __builtin_amdgcn_rcpf(1.f + __expf(-2.f * yt)) - 1.f;
            const float sg = __builtin_amdgcn_rcpf(1.f + __expf(-ys));
            const float av = th * sg;
            const int c = wv * 16 + kgrp * 4 + r;
            const int n = nt * 16 + hrow;
            const size_t gi = xbase + (size_t)c * TLEN + t0 + n;
            skip[gi] = av;
            if (!last) {
                as_[(size_t)((c >> 3) * BN + n) * 8 + (c & 7)] = f2bf(av);
            } else {
                xout[gi] = av + xin[gi];   // last layer: no 1x1
            }
        }
    }

    if (last) return;

    __syncthreads();

    // ---- 1x1: out[64][BN] = Wout[64][64] * a[64][BN] + bias + residual ----
    const unsigned short* b2 = wopk + ((size_t)(layer * 4 + wv) * 128 + lane) * 8;
    s16x8 wa2[2];
    wa2[0] = *reinterpret_cast<const s16x8*>(b2);
    wa2[1] = *reinterpret_cast<const s16x8*>(b2 + 512);
    const float* Bo = bout + (size_t)layer * CH;
    float bo[4];
    #pragma unroll
    for (int r = 0; r < 4; ++r) bo[r] = Bo[wv * 16 + kgrp * 4 + r];

    #pragma unroll
    for (int nt = 0; nt < 8; ++nt) {
        f32x4 acc = (f32x4){0.f, 0.f, 0.f, 0.f};
        #pragma unroll
        for (int ks = 0; ks < 2; ++ks) {
            const s16x8 bf = *reinterpret_cast<const s16x8*>(
                &as_[(size_t)((ks * 4 + kgrp) * BN + nt * 16 + hrow) * 8]);
            acc = __builtin_amdgcn_mfma_f32_16x16x32_bf16(wa2[ks], bf, acc, 0, 0, 0);
        }
        #pragma unroll
        for (int r = 0; r < 4; ++r) {
            const int o = wv * 16 + kgrp * 4 + r;
            const int n = nt * 16 + hrow;
            const size_t gi = xbase + (size_t)o * TLEN + t0 + n;
            xout[gi] = acc[r] + bo[r] + xin[gi];
        }
    }
}

extern "C" void kernel_launch(void* const* d_in, const int* in_sizes, int n_in,
                              void* d_out, int out_size, void* d_ws, size_t ws_size,
                              hipStream_t stream)
{
    const float* x  = (const float*)d_in[0];
    const float* wc = (const float*)d_in[1];
    const float* bc = (const float*)d_in[2];
    const float* wo = (const float*)d_in[3];
    const float* bo = (const float*)d_in[4];
    float* out = (float*)d_out;
    float* ws  = (float*)d_ws;
    const size_t plane   = (size_t)NB * CH * TLEN;        // floats per x-plane
    const size_t plane_b = plane * sizeof(float);         // 33554432 bytes

    // packed weights live in ws after the ping buffer (~560KB)
    unsigned short* wcpk = (unsigned short*)((char*)d_ws + plane_b);
    unsigned short* wopk = wcpk + NCONV;

    pack_weights<<<(NCONV + NOUT) / 256, 256, 0, stream>>>(wc, wo, wcpk, wopk);

    dim3 grid(TLEN / BN, NB), block(256);
    for (int i = 0; i < NLAYER; ++i) {
        const float* xi = (i == 0) ? x : ((i & 1) ? ws : out);
        float* xo = (i & 1) ? out : ws;
        float* skip = out + (size_t)(1 + i) * plane;
        const int d = 1 << i;
        const int last = (i == NLAYER - 1) ? 1 : 0;
        if (d <= 64)
            wavenet_layer<true><<<grid, block, 0, stream>>>(xi, xo, skip, wcpk, wopk, bc, bo, i, d, last);
        else
            wavenet_layer<false><<<grid, block, 0, stream>>>(xi, xo, skip, wcpk, wopk, bc, bo, i, d, last);
    }
}

// Round 3
// 250.257 us; speedup vs baseline: 1.6953x; 1.3324x over previous
//
#include <hip/hip_runtime.h>
#include <hip/hip_bf16.h>

// WaveNet dilated conv stack, MI355X gfx950. Round 3:
//  - intermediate x planes: bf16, time-major [T][C] in d_ws (halves plane traffic)
//  - staging via global_load_lds width-16 (per-lane global addr, linear LDS dest)
//  - last layer residual read from LDS tap-0 slice
//  - dynamic LDS sized per dilation

#define CH 64
#define TLEN 16384
#define NB 8
#define BN 128
#define NLAYER 10

typedef __attribute__((ext_vector_type(4))) float f32x4;
typedef __attribute__((ext_vector_type(8))) short s16x8;
typedef __attribute__((ext_vector_type(4))) unsigned short u16x4;

__device__ __forceinline__ unsigned short f2bf(float f) {
    union { float f; unsigned u; } v; v.f = f;
    unsigned r = v.u + 0x7fffu + ((v.u >> 16) & 1u);  // RNE
    return (unsigned short)(r >> 16);
}
__device__ __forceinline__ float bf2f(unsigned short u) {
    union { unsigned u; float f; } v; v.u = ((unsigned)u) << 16;
    return v.f;
}
__device__ __forceinline__ void gload_lds16(const void* g, void* l) {
    __builtin_amdgcn_global_load_lds(
        (const __attribute__((address_space(1))) unsigned int*)g,
        (__attribute__((address_space(3))) unsigned int*)l, 16, 0, 0);
}

#define NCONV (NLAYER * 4 * 2 * 6 * 64 * 8)   // 245760 bf16: 10x 128x192 A-frags
#define NOUT  (NLAYER * 4 * 2 * 64 * 8)       // 40960  bf16: 10x 64x64 A-frags

__global__ void pack_weights(const float* __restrict__ wconv,
                             const float* __restrict__ wout,
                             unsigned short* __restrict__ wcpk,
                             unsigned short* __restrict__ wopk)
{
    int idx = blockIdx.x * 256 + threadIdx.x;
    if (idx < NCONV) {
        int j = idx & 7, t = idx >> 3;
        int lane = t & 63; t >>= 6;
        int ks = t % 6;   t /= 6;
        int m  = t & 1;   t >>= 1;
        int wv = t & 3;   int l = t >> 2;
        int o  = (m * 4 + wv) * 16 + (lane & 15);
        int ck = ks * 32 + (lane >> 4) * 8 + j;
        int kk = ck >> 6, c = ck & 63;
        wcpk[idx] = f2bf(wconv[(((size_t)l * 128 + o) * CH + c) * 3 + (2 - kk)]);
    } else if (idx < NCONV + NOUT) {
        int id = idx - NCONV;
        int j = id & 7, t = id >> 3;
        int lane = t & 63; t >>= 6;
        int ks = t & 1;    t >>= 1;
        int wv = t & 3;    int l = t >> 2;
        int o  = wv * 16 + (lane & 15);
        int c  = ks * 32 + (lane >> 4) * 8 + j;
        wopk[id] = f2bf(wout[((size_t)l * CH + o) * CH + c]);
    }
}

// SM: 0 = layer0 (fp32 [C][T] input, single window), 1 = bf16 [T][C] single
//     2 = bf16 [T][C] triple-tap (dil >= 128)
template<int SM, bool LAST>
__global__ __launch_bounds__(256, 3)
void wavenet_layer(const void* __restrict__ xin_, void* __restrict__ xout_,
                   float* __restrict__ skip,
                   const unsigned short* __restrict__ wcpk,
                   const unsigned short* __restrict__ wopk,
                   const float* __restrict__ bconv, const float* __restrict__ bout,
                   int layer, int dil)
{
    extern __shared__ __align__(16) unsigned short xs[];
    unsigned short* as_ = xs;    // 1x1 staging aliases front 16KB (xs dead by then)

    const int tid  = threadIdx.x;
    const int lane = tid & 63;
    const int wv   = tid >> 6;
    const int hrow = lane & 15;
    const int kgrp = lane >> 4;
    const int b  = blockIdx.y;
    const int t0 = blockIdx.x * BN;
    const int NW = BN + 2 * dil;
    const size_t xbase = (size_t)b * CH * TLEN;   // element offset, both layouts

    // ---- stage X into LDS ----
    if (SM == 0) {
        const float* xin = (const float*)xin_;
        #pragma unroll
        for (int c8 = 0; c8 < 8; ++c8) {
            for (int np = tid; np < NW; np += 256) {
                const int tg = t0 - 2 * dil + np;
                s16x8 pk = {0, 0, 0, 0, 0, 0, 0, 0};
                if (tg >= 0) {
                    const float* p = xin + xbase + (size_t)(c8 * 8) * TLEN + tg;
                    #pragma unroll
                    for (int j = 0; j < 8; ++j) pk[j] = (short)f2bf(p[(size_t)j * TLEN]);
                }
                *reinterpret_cast<s16x8*>(&xs[(size_t)(c8 * NW + np) * 8]) = pk;
            }
        }
    } else if (SM == 1) {
        const unsigned short* xin = (const unsigned short*)xin_;
        const int cnt_n = (NW + 63) >> 6;
        if (t0 >= 2 * dil) {
            for (int ch = wv; ch < 8 * cnt_n; ch += 4) {
                const int c8 = ch / cnt_n;
                const int n0 = (ch % cnt_n) * 64;
                const int rem = NW - n0;
                const unsigned short* src =
                    xin + xbase + (size_t)(t0 - 2 * dil + n0 + lane) * CH + c8 * 8;
                unsigned short* dst = &xs[(size_t)(c8 * NW + n0) * 8];
                if (rem >= 64) gload_lds16(src, dst);
                else if (lane < rem) gload_lds16(src, dst);
            }
        } else {
            for (int ch = wv; ch < 8 * cnt_n; ch += 4) {
                const int c8 = ch / cnt_n;
                const int n0 = (ch % cnt_n) * 64;
                if (n0 + lane < NW) {
                    const int tg = t0 - 2 * dil + n0 + lane;
                    s16x8 pk = {0, 0, 0, 0, 0, 0, 0, 0};
                    if (tg >= 0)
                        pk = *reinterpret_cast<const s16x8*>(xin + xbase + (size_t)tg * CH + c8 * 8);
                    *reinterpret_cast<s16x8*>(&xs[(size_t)(c8 * NW + n0 + lane) * 8]) = pk;
                }
            }
        }
    } else {
        const unsigned short* xin = (const unsigned short*)xin_;
        if (t0 >= 2 * dil) {
            for (int ch = wv; ch < 48; ch += 4) {
                const int kk = ch >> 4, c8 = (ch >> 1) & 7, n0 = (ch & 1) * 64;
                const unsigned short* src =
                    xin + xbase + (size_t)(t0 + n0 + lane - kk * dil) * CH + c8 * 8;
                unsigned short* dst = &xs[(size_t)((kk * 8 + c8) * BN + n0) * 8];
                gload_lds16(src, dst);
            }
        } else {
            for (int ch = wv; ch < 48; ch += 4) {
                const int kk = ch >> 4, c8 = (ch >> 1) & 7, n0 = (ch & 1) * 64;
                const int tg = t0 + n0 + lane - kk * dil;
                s16x8 pk = {0, 0, 0, 0, 0, 0, 0, 0};
                if (tg >= 0)
                    pk = *reinterpret_cast<const s16x8*>(xin + xbase + (size_t)tg * CH + c8 * 8);
                *reinterpret_cast<s16x8*>(&xs[(size_t)((kk * 8 + c8) * BN + n0 + lane) * 8]) = pk;
            }
        }
    }

    // ---- conv A-fragments (packed, 16B vector loads) ----
    s16x8 wa[2][6];
    {
        const unsigned short* base = wcpk + ((size_t)(layer * 4 + wv) * 768 + lane) * 8;
        #pragma unroll
        for (int m = 0; m < 2; ++m)
            #pragma unroll
            for (int ks = 0; ks < 6; ++ks)
                wa[m][ks] = *reinterpret_cast<const s16x8*>(base + (size_t)(m * 6 + ks) * 512);
    }
    const float* Bc = bconv + (size_t)layer * 128;
    float bt[4], bs[4];
    #pragma unroll
    for (int r = 0; r < 4; ++r) {
        bt[r] = Bc[wv * 16 + kgrp * 4 + r];
        bs[r] = Bc[64 + wv * 16 + kgrp * 4 + r];
    }

    __syncthreads();

    // ---- conv GEMM: Y[128][BN] = W~[128][192] * X~[192][BN] ----
    f32x4 accT[8], accS[8];
    #pragma unroll
    for (int nt = 0; nt < 8; ++nt) {
        accT[nt] = (f32x4){0.f, 0.f, 0.f, 0.f};
        accS[nt] = (f32x4){0.f, 0.f, 0.f, 0.f};
    }
    #pragma unroll
    for (int nt = 0; nt < 8; ++nt) {
        #pragma unroll
        for (int ks = 0; ks < 6; ++ks) {
            const int kb = ks * 4 + kgrp;
            const unsigned short* bp;
            if (SM == 2) {
                bp = &xs[(size_t)(kb * BN + nt * 16 + hrow) * 8];
            } else {
                const int kk = kb >> 3, c8i = kb & 7;
                bp = &xs[(size_t)(c8i * NW + nt * 16 + hrow + (2 - kk) * dil) * 8];
            }
            const s16x8 bf = *reinterpret_cast<const s16x8*>(bp);
            accT[nt] = __builtin_amdgcn_mfma_f32_16x16x32_bf16(wa[0][ks], bf, accT[nt], 0, 0, 0);
            accS[nt] = __builtin_amdgcn_mfma_f32_16x16x32_bf16(wa[1][ks], bf, accS[nt], 0, 0, 0);
        }
    }

    if (!LAST) __syncthreads();   // xs reads complete before as_ alias writes

    // ---- gated activation + skip write ----
    // C/D: col n = lane&15, row = (lane>>4)*4 + r
    #pragma unroll
    for (int nt = 0; nt < 8; ++nt) {
        #pragma unroll
        for (int r = 0; r < 4; ++r) {
            const float yt = accT[nt][r] + bt[r];
            const float ys = accS[nt][r] + bs[r];
            const float th = 2.f * __builtin_amdgcn_rcpf(1.f + __expf(-2.f * yt)) - 1.f;
            const float sg = __builtin_amdgcn_rcpf(1.f + __expf(-ys));
            const float av = th * sg;
            const int c = wv * 16 + kgrp * 4 + r;
            const int n = nt * 16 + hrow;
            skip[xbase + (size_t)c * TLEN + t0 + n] = av;
            if (LAST) {
                // residual from LDS tap-0 slice (kk=0 holds x[t0+n])
                const float res = bf2f(xs[(size_t)((c >> 3) * BN + n) * 8 + (c & 7)]);
                ((float*)xout_)[xbase + (size_t)c * TLEN + t0 + n] = av + res;
            } else {
                as_[(size_t)((c >> 3) * BN + n) * 8 + (c & 7)] = f2bf(av);
            }
        }
    }

    if (LAST) return;

    __syncthreads();

    // ---- 1x1: out = Wout * a + bias + residual, stored bf16 [T][C] ----
    const unsigned short* b2 = wopk + ((size_t)(layer * 4 + wv) * 128 + lane) * 8;
    s16x8 wa2[2];
    wa2[0] = *reinterpret_cast<const s16x8*>(b2);
    wa2[1] = *reinterpret_cast<const s16x8*>(b2 + 512);
    const float* Bo = bout + (size_t)layer * CH;
    float bo[4];
    #pragma unroll
    for (int r = 0; r < 4; ++r) bo[r] = Bo[wv * 16 + kgrp * 4 + r];

    const int o0 = wv * 16 + kgrp * 4;
    unsigned short* xout = (unsigned short*)xout_;

    #pragma unroll
    for (int nt = 0; nt < 8; ++nt) {
        f32x4 acc = (f32x4){0.f, 0.f, 0.f, 0.f};
        #pragma unroll
        for (int ks = 0; ks < 2; ++ks) {
            const s16x8 bf = *reinterpret_cast<const s16x8*>(
                &as_[(size_t)((ks * 4 + kgrp) * BN + nt * 16 + hrow) * 8]);
            acc = __builtin_amdgcn_mfma_f32_16x16x32_bf16(wa2[ks], bf, acc, 0, 0, 0);
        }
        const int n = nt * 16 + hrow;
        float res[4];
        if (SM == 0) {
            const float* xin = (const float*)xin_;
            #pragma unroll
            for (int r = 0; r < 4; ++r)
                res[r] = xin[xbase + (size_t)(o0 + r) * TLEN + t0 + n];
        } else {
            const u16x4 rv = *reinterpret_cast<const u16x4*>(
                (const unsigned short*)xin_ + xbase + (size_t)(t0 + n) * CH + o0);
            #pragma unroll
            for (int r = 0; r < 4; ++r) res[r] = bf2f(rv[r]);
        }
        u16x4 ov;
        #pragma unroll
        for (int r = 0; r < 4; ++r) ov[r] = f2bf(acc[r] + bo[r] + res[r]);
        *reinterpret_cast<u16x4*>(&xout[xbase + (size_t)(t0 + n) * CH + o0]) = ov;
    }
}

extern "C" void kernel_launch(void* const* d_in, const int* in_sizes, int n_in,
                              void* d_out, int out_size, void* d_ws, size_t ws_size,
                              hipStream_t stream)
{
    const float* x  = (const float*)d_in[0];
    const float* wc = (const float*)d_in[1];
    const float* bc = (const float*)d_in[2];
    const float* wo = (const float*)d_in[3];
    const float* bo = (const float*)d_in[4];
    float* out = (float*)d_out;
    const size_t planeF  = (size_t)NB * CH * TLEN;            // fp32 elems per plane
    const size_t planeBy = planeF * sizeof(unsigned short);   // bf16 plane bytes

    unsigned short* P0 = (unsigned short*)d_ws;
    unsigned short* P1 = (unsigned short*)((char*)d_ws + planeBy);
    unsigned short* wcpk = (unsigned short*)((char*)d_ws + 2 * planeBy);
    unsigned short* wopk = wcpk + NCONV;

    pack_weights<<<(NCONV + NOUT) / 256, 256, 0, stream>>>(wc, wo, wcpk, wopk);

    dim3 grid(TLEN / BN, NB), block(256);

    // layer 0: fp32 [C][T] input -> P0
    wavenet_layer<0, false><<<grid, block, 130 * 128, stream>>>(
        x, P0, out + planeF, wcpk, wopk, bc, bo, 0, 1);

    for (int i = 1; i < NLAYER - 1; ++i) {
        const int d = 1 << i;
        const void* xi = (i & 1) ? (void*)P0 : (void*)P1;
        void* xo = (i & 1) ? (void*)P1 : (void*)P0;
        float* skip = out + (size_t)(1 + i) * planeF;
        if (d <= 64)
            wavenet_layer<1, false><<<grid, block, (size_t)(BN + 2 * d) * 128, stream>>>(
                xi, xo, skip, wcpk, wopk, bc, bo, i, d);
        else
            wavenet_layer<2, false><<<grid, block, 24 * BN * 8 * 2, stream>>>(
                xi, xo, skip, wcpk, wopk, bc, bo, i, d);
    }

    // layer 9: triple-tap, residual from LDS, fp32 [C][T] out slot 0
    wavenet_layer<2, true><<<grid, block, 24 * BN * 8 * 2, stream>>>(
        P0, out, out + (size_t)NLAYER * planeF, wcpk, wopk, bc, bo, 9, 512);
}

// Round 5
// 248.159 us; speedup vs baseline: 1.7096x; 1.0085x over previous
//
#include <hip/hip_runtime.h>
#include <hip/hip_bf16.h>

// WaveNet dilated conv stack, MI355X gfx950. Round 5 (= round 4 design, compile fix):
//  - layers 0-4 (d=1..16, halo 62) fused into ONE kernel, chained in LDS
//    (192-wide bf16 window, ping-pong planes, chunked 1x1 staging)
//  - layers 5-9 per-layer kernels (round-3, proven)
//  - plane stride 194 / as_ stride 130: conflict-free ds_read_b128

#define CH 64
#define TLEN 16384
#define NB 8
#define BN 128
#define NLAYER 10

#define WP   192   // fused plane columns (col p <-> time t0-64+p)
#define PSTR 194   // plane row stride (cols): 194*16B % 128 = 32 -> bank spread
#define ASTR 130   // as_ row stride: 130*16B % 128 = 32 -> bank spread

typedef __attribute__((ext_vector_type(4))) float f32x4;
typedef __attribute__((ext_vector_type(8))) short s16x8;
typedef __attribute__((ext_vector_type(4))) unsigned short u16x4;

__device__ __forceinline__ unsigned short f2bf(float f) {
    union { float f; unsigned u; } v; v.f = f;
    unsigned r = v.u + 0x7fffu + ((v.u >> 16) & 1u);  // RNE
    return (unsigned short)(r >> 16);
}
__device__ __forceinline__ float bf2f(unsigned short u) {
    union { unsigned u; float f; } v; v.u = ((unsigned)u) << 16;
    return v.f;
}
__device__ __forceinline__ void gload_lds16(const void* g, void* l) {
    __builtin_amdgcn_global_load_lds(
        (const __attribute__((address_space(1))) unsigned int*)g,
        (__attribute__((address_space(3))) unsigned int*)l, 16, 0, 0);
}

#define NCONV (NLAYER * 4 * 2 * 6 * 64 * 8)   // 245760 bf16: 10x 128x192 A-frags
#define NOUT  (NLAYER * 4 * 2 * 64 * 8)       // 40960  bf16: 10x 64x64 A-frags

__global__ void pack_weights(const float* __restrict__ wconv,
                             const float* __restrict__ wout,
                             unsigned short* __restrict__ wcpk,
                             unsigned short* __restrict__ wopk)
{
    int idx = blockIdx.x * 256 + threadIdx.x;
    if (idx < NCONV) {
        int j = idx & 7, t = idx >> 3;
        int lane = t & 63; t >>= 6;
        int ks = t % 6;   t /= 6;
        int m  = t & 1;   t >>= 1;
        int wv = t & 3;   int l = t >> 2;
        int o  = (m * 4 + wv) * 16 + (lane & 15);
        int ck = ks * 32 + (lane >> 4) * 8 + j;
        int kk = ck >> 6, c = ck & 63;
        wcpk[idx] = f2bf(wconv[(((size_t)l * 128 + o) * CH + c) * 3 + (2 - kk)]);
    } else if (idx < NCONV + NOUT) {
        int id = idx - NCONV;
        int j = id & 7, t = id >> 3;
        int lane = t & 63; t >>= 6;
        int ks = t & 1;    t >>= 1;
        int wv = t & 3;    int l = t >> 2;
        int o  = wv * 16 + (lane & 15);
        int c  = ks * 32 + (lane >> 4) * 8 + j;
        wopk[id] = f2bf(wout[((size_t)l * CH + o) * CH + c]);
    }
}

// ---------------- fused head: layers 0..4 (d = 1,2,4,8,16) ----------------
__global__ __launch_bounds__(256, 2)
void wavenet_head(const float* __restrict__ x, unsigned short* __restrict__ xplane,
                  float* __restrict__ out,
                  const unsigned short* __restrict__ wcpk,
                  const unsigned short* __restrict__ wopk,
                  const float* __restrict__ bconv, const float* __restrict__ bout)
{
    __shared__ __align__(16) unsigned short pl[2][8 * PSTR * 8];   // 2 x 24832 B
    __shared__ __align__(16) unsigned short as_[8 * ASTR * 8];     // 16640 B

    const int tid  = threadIdx.x;
    const int lane = tid & 63;
    const int wv   = tid >> 6;
    const int hrow = lane & 15;
    const int kgrp = lane >> 4;
    const int b  = blockIdx.y;
    const int t0 = blockIdx.x * BN;
    const size_t xbase  = (size_t)b * CH * TLEN;
    const size_t planeF = (size_t)NB * CH * TLEN;

    // ---- stage input window: col p in [0,192), time tt = t0 - 64 + p ----
    if (tid < WP) {
        const int tt = t0 - 64 + tid;
        #pragma unroll
        for (int c8 = 0; c8 < 8; ++c8) {
            s16x8 pk = {0, 0, 0, 0, 0, 0, 0, 0};
            if (tt >= 0) {
                const float* p = x + xbase + (size_t)(c8 * 8) * TLEN + tt;
                #pragma unroll
                for (int j = 0; j < 8; ++j) pk[j] = (short)f2bf(p[(size_t)j * TLEN]);
            }
            *reinterpret_cast<s16x8*>(&pl[0][(size_t)(c8 * PSTR + tid) * 8]) = pk;
        }
    }
    __syncthreads();

    int cur = 0;
    for (int l = 0; l < 5; ++l) {
        const int dil = 1 << l;
        unsigned short* plc = pl[cur];
        unsigned short* pln = pl[cur ^ 1];

        // weights + biases for this layer
        s16x8 wa[2][6];
        {
            const unsigned short* basew = wcpk + ((size_t)(l * 4 + wv) * 768 + lane) * 8;
            #pragma unroll
            for (int m = 0; m < 2; ++m)
                #pragma unroll
                for (int ks = 0; ks < 6; ++ks)
                    wa[m][ks] = *reinterpret_cast<const s16x8*>(basew + (size_t)(m * 6 + ks) * 512);
        }
        const float* Bc = bconv + (size_t)l * 128;
        float bt[4], bs[4];
        #pragma unroll
        for (int r = 0; r < 4; ++r) {
            bt[r] = Bc[wv * 16 + kgrp * 4 + r];
            bs[r] = Bc[64 + wv * 16 + kgrp * 4 + r];
        }
        s16x8 wa2[2];
        {
            const unsigned short* b2 = wopk + ((size_t)(l * 4 + wv) * 128 + lane) * 8;
            wa2[0] = *reinterpret_cast<const s16x8*>(b2);
            wa2[1] = *reinterpret_cast<const s16x8*>(b2 + 512);
        }
        const float* Bo = bout + (size_t)l * CH;
        float bo[4];
        #pragma unroll
        for (int r = 0; r < 4; ++r) bo[r] = Bo[wv * 16 + kgrp * 4 + r];

        // ---- conv GEMM over all 12 n-tiles (cols 0..191) ----
        f32x4 accT[12], accS[12];
        #pragma unroll
        for (int nt = 0; nt < 12; ++nt) {
            accT[nt] = (f32x4){0.f, 0.f, 0.f, 0.f};
            accS[nt] = (f32x4){0.f, 0.f, 0.f, 0.f};
        }
        #pragma unroll
        for (int nt = 0; nt < 12; ++nt) {
            #pragma unroll
            for (int ks = 0; ks < 6; ++ks) {
                const int kb = ks * 4 + kgrp;
                const int kk = kb >> 3, c8i = kb & 7;
                int q = nt * 16 + hrow - kk * dil;
                if (q < 0) q = 0;   // garbage halo cols only; never read by valid cols
                const s16x8 bf = *reinterpret_cast<const s16x8*>(&plc[(size_t)(c8i * PSTR + q) * 8]);
                accT[nt] = __builtin_amdgcn_mfma_f32_16x16x32_bf16(wa[0][ks], bf, accT[nt], 0, 0, 0);
                accS[nt] = __builtin_amdgcn_mfma_f32_16x16x32_bf16(wa[1][ks], bf, accS[nt], 0, 0, 0);
            }
        }

        float* skipl = out + (size_t)(1 + l) * planeF + xbase;
        const int o0 = wv * 16 + kgrp * 4;

        // ---- chunk 0: activation for tiles 0..7 (cols 0..127) ----
        #pragma unroll
        for (int nt = 0; nt < 8; ++nt) {
            #pragma unroll
            for (int r = 0; r < 4; ++r) {
                const float yt = accT[nt][r] + bt[r];
                const float ys = accS[nt][r] + bs[r];
                const float th = 2.f * __builtin_amdgcn_rcpf(1.f + __expf(-2.f * yt)) - 1.f;
                const float sg = __builtin_amdgcn_rcpf(1.f + __expf(-ys));
                const float av = th * sg;
                const int c = wv * 16 + kgrp * 4 + r;
                const int p = nt * 16 + hrow;
                if (nt >= 4) skipl[(size_t)c * TLEN + t0 + p - 64] = av;
                as_[(size_t)((c >> 3) * ASTR + p) * 8 + (c & 7)] = f2bf(av);
            }
        }
        __syncthreads();
        // ---- chunk 0: 1x1 for tiles 0..7 ----
        #pragma unroll
        for (int nt = 0; nt < 8; ++nt) {
            f32x4 a2 = (f32x4){0.f, 0.f, 0.f, 0.f};
            const int p = nt * 16 + hrow;
            #pragma unroll
            for (int ks2 = 0; ks2 < 2; ++ks2) {
                const s16x8 bf = *reinterpret_cast<const s16x8*>(
                    &as_[(size_t)((ks2 * 4 + kgrp) * ASTR + p) * 8]);
                a2 = __builtin_amdgcn_mfma_f32_16x16x32_bf16(wa2[ks2], bf, a2, 0, 0, 0);
            }
            const int tt = t0 - 64 + p;
            const u16x4 rv = *reinterpret_cast<const u16x4*>(
                &plc[(size_t)((o0 >> 3) * PSTR + p) * 8 + (o0 & 7)]);
            if (l == 4) {
                if (nt >= 4) {
                    u16x4 ov;
                    #pragma unroll
                    for (int r = 0; r < 4; ++r) ov[r] = f2bf(a2[r] + bo[r] + bf2f(rv[r]));
                    *reinterpret_cast<u16x4*>(&xplane[xbase + (size_t)tt * CH + o0]) = ov;
                }
            } else {
                u16x4 ov;
                #pragma unroll
                for (int r = 0; r < 4; ++r)
                    ov[r] = (tt >= 0) ? f2bf(a2[r] + bo[r] + bf2f(rv[r])) : (unsigned short)0;
                *reinterpret_cast<u16x4*>(&pln[(size_t)((o0 >> 3) * PSTR + p) * 8 + (o0 & 7)]) = ov;
            }
        }
        __syncthreads();
        // ---- chunk 1: activation for tiles 8..11 (cols 128..191) ----
        #pragma unroll
        for (int nt = 8; nt < 12; ++nt) {
            #pragma unroll
            for (int r = 0; r < 4; ++r) {
                const float yt = accT[nt][r] + bt[r];
                const float ys = accS[nt][r] + bs[r];
                const float th = 2.f * __builtin_amdgcn_rcpf(1.f + __expf(-2.f * yt)) - 1.f;
                const float sg = __builtin_amdgcn_rcpf(1.f + __expf(-ys));
                const float av = th * sg;
                const int c = wv * 16 + kgrp * 4 + r;
                const int p = nt * 16 + hrow;
                skipl[(size_t)c * TLEN + t0 + p - 64] = av;
                as_[(size_t)((c >> 3) * ASTR + p - 128) * 8 + (c & 7)] = f2bf(av);
            }
        }
        __syncthreads();
        // ---- chunk 1: 1x1 for tiles 8..11 ----
        #pragma unroll
        for (int nt = 8; nt < 12; ++nt) {
            f32x4 a2 = (f32x4){0.f, 0.f, 0.f, 0.f};
            const int p = nt * 16 + hrow;
            #pragma unroll
            for (int ks2 = 0; ks2 < 2; ++ks2) {
                const s16x8 bf = *reinterpret_cast<const s16x8*>(
                    &as_[(size_t)((ks2 * 4 + kgrp) * ASTR + p - 128) * 8]);
                a2 = __builtin_amdgcn_mfma_f32_16x16x32_bf16(wa2[ks2], bf, a2, 0, 0, 0);
            }
            const int tt = t0 - 64 + p;
            const u16x4 rv = *reinterpret_cast<const u16x4*>(
                &plc[(size_t)((o0 >> 3) * PSTR + p) * 8 + (o0 & 7)]);
            if (l == 4) {
                u16x4 ov;
                #pragma unroll
                for (int r = 0; r < 4; ++r) ov[r] = f2bf(a2[r] + bo[r] + bf2f(rv[r]));
                *reinterpret_cast<u16x4*>(&xplane[xbase + (size_t)tt * CH + o0]) = ov;
            } else {
                u16x4 ov;
                #pragma unroll
                for (int r = 0; r < 4; ++r) ov[r] = f2bf(a2[r] + bo[r] + bf2f(rv[r]));
                *reinterpret_cast<u16x4*>(&pln[(size_t)((o0 >> 3) * PSTR + p) * 8 + (o0 & 7)]) = ov;
            }
        }
        __syncthreads();

        cur ^= 1;
    }
}

// ------------- tail layers 5..9: per-layer kernels (round-3) -------------
// SM: 1 = bf16 [T][C] single window (dil<=64), 2 = bf16 [T][C] triple-tap
template<int SM, bool LAST>
__global__ __launch_bounds__(256, 3)
void wavenet_layer(const void* __restrict__ xin_, void* __restrict__ xout_,
                   float* __restrict__ skip,
                   const unsigned short* __restrict__ wcpk,
                   const unsigned short* __restrict__ wopk,
                   const float* __restrict__ bconv, const float* __restrict__ bout,
                   int layer, int dil)
{
    extern __shared__ __align__(16) unsigned short xs[];
    unsigned short* as_ = xs;    // 1x1 staging aliases front 16KB (xs dead by then)

    const int tid  = threadIdx.x;
    const int lane = tid & 63;
    const int wv   = tid >> 6;
    const int hrow = lane & 15;
    const int kgrp = lane >> 4;
    const int b  = blockIdx.y;
    const int t0 = blockIdx.x * BN;
    const int NW = BN + 2 * dil;
    const size_t xbase = (size_t)b * CH * TLEN;

    // ---- stage X into LDS ----
    if (SM == 1) {
        const unsigned short* xin = (const unsigned short*)xin_;
        const int cnt_n = (NW + 63) >> 6;
        if (t0 >= 2 * dil) {
            for (int ch = wv; ch < 8 * cnt_n; ch += 4) {
                const int c8 = ch / cnt_n;
                const int n0 = (ch % cnt_n) * 64;
                const int rem = NW - n0;
                const unsigned short* src =
                    xin + xbase + (size_t)(t0 - 2 * dil + n0 + lane) * CH + c8 * 8;
                unsigned short* dst = &xs[(size_t)(c8 * NW + n0) * 8];
                if (rem >= 64) gload_lds16(src, dst);
                else if (lane < rem) gload_lds16(src, dst);
            }
        } else {
            for (int ch = wv; ch < 8 * cnt_n; ch += 4) {
                const int c8 = ch / cnt_n;
                const int n0 = (ch % cnt_n) * 64;
                if (n0 + lane < NW) {
                    const int tg = t0 - 2 * dil + n0 + lane;
                    s16x8 pk = {0, 0, 0, 0, 0, 0, 0, 0};
                    if (tg >= 0)
                        pk = *reinterpret_cast<const s16x8*>(xin + xbase + (size_t)tg * CH + c8 * 8);
                    *reinterpret_cast<s16x8*>(&xs[(size_t)(c8 * NW + n0 + lane) * 8]) = pk;
                }
            }
        }
    } else {
        const unsigned short* xin = (const unsigned short*)xin_;
        if (t0 >= 2 * dil) {
            for (int ch = wv; ch < 48; ch += 4) {
                const int kk = ch >> 4, c8 = (ch >> 1) & 7, n0 = (ch & 1) * 64;
                const unsigned short* src =
                    xin + xbase + (size_t)(t0 + n0 + lane - kk * dil) * CH + c8 * 8;
                unsigned short* dst = &xs[(size_t)((kk * 8 + c8) * BN + n0) * 8];
                gload_lds16(src, dst);
            }
        } else {
            for (int ch = wv; ch < 48; ch += 4) {
                const int kk = ch >> 4, c8 = (ch >> 1) & 7, n0 = (ch & 1) * 64;
                const int tg = t0 + n0 + lane - kk * dil;
                s16x8 pk = {0, 0, 0, 0, 0, 0, 0, 0};
                if (tg >= 0)
                    pk = *reinterpret_cast<const s16x8*>(xin + xbase + (size_t)tg * CH + c8 * 8);
                *reinterpret_cast<s16x8*>(&xs[(size_t)((kk * 8 + c8) * BN + n0 + lane) * 8]) = pk;
            }
        }
    }

    // ---- conv A-fragments (packed, 16B vector loads) ----
    s16x8 wa[2][6];
    {
        const unsigned short* base = wcpk + ((size_t)(layer * 4 + wv) * 768 + lane) * 8;
        #pragma unroll
        for (int m = 0; m < 2; ++m)
            #pragma unroll
            for (int ks = 0; ks < 6; ++ks)
                wa[m][ks] = *reinterpret_cast<const s16x8*>(base + (size_t)(m * 6 + ks) * 512);
    }
    const float* Bc = bconv + (size_t)layer * 128;
    float bt[4], bs[4];
    #pragma unroll
    for (int r = 0; r < 4; ++r) {
        bt[r] = Bc[wv * 16 + kgrp * 4 + r];
        bs[r] = Bc[64 + wv * 16 + kgrp * 4 + r];
    }

    __syncthreads();

    // ---- conv GEMM: Y[128][BN] = W~[128][192] * X~[192][BN] ----
    f32x4 accT[8], accS[8];
    #pragma unroll
    for (int nt = 0; nt < 8; ++nt) {
        accT[nt] = (f32x4){0.f, 0.f, 0.f, 0.f};
        accS[nt] = (f32x4){0.f, 0.f, 0.f, 0.f};
    }
    #pragma unroll
    for (int nt = 0; nt < 8; ++nt) {
        #pragma unroll
        for (int ks = 0; ks < 6; ++ks) {
            const int kb = ks * 4 + kgrp;
            const unsigned short* bp;
            if (SM == 2) {
                bp = &xs[(size_t)(kb * BN + nt * 16 + hrow) * 8];
            } else {
                const int kk = kb >> 3, c8i = kb & 7;
                bp = &xs[(size_t)(c8i * NW + nt * 16 + hrow + (2 - kk) * dil) * 8];
            }
            const s16x8 bf = *reinterpret_cast<const s16x8*>(bp);
            accT[nt] = __builtin_amdgcn_mfma_f32_16x16x32_bf16(wa[0][ks], bf, accT[nt], 0, 0, 0);
            accS[nt] = __builtin_amdgcn_mfma_f32_16x16x32_bf16(wa[1][ks], bf, accS[nt], 0, 0, 0);
        }
    }

    if (!LAST) __syncthreads();   // xs reads complete before as_ alias writes

    // ---- gated activation + skip write ----
    #pragma unroll
    for (int nt = 0; nt < 8; ++nt) {
        #pragma unroll
        for (int r = 0; r < 4; ++r) {
            const float yt = accT[nt][r] + bt[r];
            const float ys = accS[nt][r] + bs[r];
            const float th = 2.f * __builtin_amdgcn_rcpf(1.f + __expf(-2.f * yt)) - 1.f;
            const float sg = __builtin_amdgcn_rcpf(1.f + __expf(-ys));
            const float av = th * sg;
            const int c = wv * 16 + kgrp * 4 + r;
            const int n = nt * 16 + hrow;
            skip[xbase + (size_t)c * TLEN + t0 + n] = av;
            if (LAST) {
                const float res = bf2f(xs[(size_t)((c >> 3) * BN + n) * 8 + (c & 7)]);
                ((float*)xout_)[xbase + (size_t)c * TLEN + t0 + n] = av + res;
            } else {
                as_[(size_t)((c >> 3) * BN + n) * 8 + (c & 7)] = f2bf(av);
            }
        }
    }

    if (LAST) return;

    __syncthreads();

    // ---- 1x1: out = Wout * a + bias + residual, stored bf16 [T][C] ----
    const unsigned short* b2 = wopk + ((size_t)(layer * 4 + wv) * 128 + lane) * 8;
    s16x8 wa2[2];
    wa2[0] = *reinterpret_cast<const s16x8*>(b2);
    wa2[1] = *reinterpret_cast<const s16x8*>(b2 + 512);
    const float* Bo = bout + (size_t)layer * CH;
    float bo[4];
    #pragma unroll
    for (int r = 0; r < 4; ++r) bo[r] = Bo[wv * 16 + kgrp * 4 + r];

    const int o0 = wv * 16 + kgrp * 4;
    unsigned short* xout = (unsigned short*)xout_;

    #pragma unroll
    for (int nt = 0; nt < 8; ++nt) {
        f32x4 acc = (f32x4){0.f, 0.f, 0.f, 0.f};
        #pragma unroll
        for (int ks = 0; ks < 2; ++ks) {
            const s16x8 bf = *reinterpret_cast<const s16x8*>(
                &as_[(size_t)((ks * 4 + kgrp) * BN + nt * 16 + hrow) * 8]);
            acc = __builtin_amdgcn_mfma_f32_16x16x32_bf16(wa2[ks], bf, acc, 0, 0, 0);
        }
        const int n = nt * 16 + hrow;
        const u16x4 rv = *reinterpret_cast<const u16x4*>(
            (const unsigned short*)xin_ + xbase + (size_t)(t0 + n) * CH + o0);
        u16x4 ov;
        #pragma unroll
        for (int r = 0; r < 4; ++r) ov[r] = f2bf(acc[r] + bo[r] + bf2f(rv[r]));
        *reinterpret_cast<u16x4*>(&xout[xbase + (size_t)(t0 + n) * CH + o0]) = ov;
    }
}

extern "C" void kernel_launch(void* const* d_in, const int* in_sizes, int n_in,
                              void* d_out, int out_size, void* d_ws, size_t ws_size,
                              hipStream_t stream)
{
    const float* x  = (const float*)d_in[0];
    const float* wc = (const float*)d_in[1];
    const float* bc = (const float*)d_in[2];
    const float* wo = (const float*)d_in[3];
    const float* bo = (const float*)d_in[4];
    float* out = (float*)d_out;
    const size_t planeF  = (size_t)NB * CH * TLEN;
    const size_t planeBy = planeF * sizeof(unsigned short);

    unsigned short* P0 = (unsigned short*)d_ws;
    unsigned short* P1 = (unsigned short*)((char*)d_ws + planeBy);
    unsigned short* wcpk = (unsigned short*)((char*)d_ws + 2 * planeBy);
    unsigned short* wopk = wcpk + NCONV;

    pack_weights<<<(NCONV + NOUT) / 256, 256, 0, stream>>>(wc, wo, wcpk, wopk);

    dim3 grid(TLEN / BN, NB), block(256);

    // layers 0-4 fused: fp32 x -> skips 1..5 + bf16 plane P0
    wavenet_head<<<grid, block, 0, stream>>>(x, P0, out, wcpk, wopk, bc, bo);

    // layer 5 (d=32), 6 (d=64): single-window
    wavenet_layer<1, false><<<grid, block, (size_t)(BN + 64) * 128, stream>>>(
        P0, P1, out + 6 * planeF, wcpk, wopk, bc, bo, 5, 32);
    wavenet_layer<1, false><<<grid, block, (size_t)(BN + 128) * 128, stream>>>(
        P1, P0, out + 7 * planeF, wcpk, wopk, bc, bo, 6, 64);
    // layer 7 (d=128), 8 (d=256): triple-tap
    wavenet_layer<2, false><<<grid, block, 24 * BN * 8 * 2, stream>>>(
        P0, P1, out + 8 * planeF, wcpk, wopk, bc, bo, 7, 128);
    wavenet_layer<2, false><<<grid, block, 24 * BN * 8 * 2, stream>>>(
        P1, P0, out + 9 * planeF, wcpk, wopk, bc, bo, 8, 256);
    // layer 9 (d=512): triple-tap, residual from LDS, fp32 out slot 0
    wavenet_layer<2, true><<<grid, block, 24 * BN * 8 * 2, stream>>>(
        P0, out, out + 10 * planeF, wcpk, wopk, bc, bo, 9, 512);
}